// Round 17
// baseline (32.435 us; speedup 1.0000x reference)
//
#include <hip/hip_runtime.h>

// MultiHeadRouter: B=2, L=4096, H=16, S=64, D=128
// out (float32): [T*H ones][T*H argmax-as-float][1 loss], T = 8192
//
// R17 = R16 core with the serial pipeline compressed:
// - prep_w FUSED into the router (per-block W->LDS conversion; W is L2-hot).
// - W,bias pre-scaled by log2(e) during conversion -> exp2f (native v_exp).
//   Argmax is scale-invariant; same error magnitude as the verified split.
// - finale at full width: 257 blocks (was 33), coalesced transpose via LDS.
// - rep zeroed by a 64 KB memset node.
// 32x32x16 swapped-operand MFMA core + register-local argmax + DPP score
// sums bit-identical to R16 (absmax 0).

#define TOKENS  8192
#define NHEAD   16
#define NSTATE  64
#define DDIM    128
#define TH      (TOKENS * NHEAD)

// d_ws layout
#define REP_BYTES 65536                  // repf[8][1024] + repc[8][1024]
#define IDX_OFF   REP_BYTES              // idx_scr[16][8192] floats = 512 KB

#define LOG2E 1.4426950408889634f

typedef _Float16 half8  __attribute__((ext_vector_type(8)));
typedef float    f32x4  __attribute__((ext_vector_type(4)));
typedef float    f32x16 __attribute__((ext_vector_type(16)));

__device__ __forceinline__ void split8(const f32x4 v0, const f32x4 v1,
                                       half8& hh, half8& ll) {
    #pragma unroll
    for (int j = 0; j < 4; ++j) {
        _Float16 h0 = (_Float16)v0[j];
        hh[j]     = h0;  ll[j]     = (_Float16)(v0[j] - (float)h0);
        _Float16 h1 = (_Float16)v1[j];
        hh[4 + j] = h1;  ll[4 + j] = (_Float16)(v1[j] - (float)h1);
    }
}

// sum over each 32-lane half via DPP (VALU pipe). Valid in lanes 31/63.
__device__ __forceinline__ float dpp_sum32(float v) {
    float t;
    t = __int_as_float(__builtin_amdgcn_update_dpp(0, __float_as_int(v), 0x111, 0xf, 0xf, true)); v += t;
    t = __int_as_float(__builtin_amdgcn_update_dpp(0, __float_as_int(v), 0x112, 0xf, 0xf, true)); v += t;
    t = __int_as_float(__builtin_amdgcn_update_dpp(0, __float_as_int(v), 0x114, 0xf, 0xf, true)); v += t;
    t = __int_as_float(__builtin_amdgcn_update_dpp(0, __float_as_int(v), 0x118, 0xf, 0xf, true)); v += t;
    t = __int_as_float(__builtin_amdgcn_update_dpp(0, __float_as_int(v), 0x142, 0xf, 0xf, true)); v += t;
    return v;
}

__global__ __launch_bounds__(256)
void router_all(const float* __restrict__ x,     // [T,H,D]
                const float* __restrict__ w,     // [H,S,D]
                const float* __restrict__ bias,  // [H,S]
                float* __restrict__ idx_scr,     // [H][T]
                float* __restrict__ repf,        // [8][1024]
                float* __restrict__ repc)        // [8][1024]
{
    // 32 KB W fragment planes (R16 layout) + bias + hist + per-wave sums
    __shared__ __align__(16) unsigned char smem[32768];
    __shared__ float        lds_bias[64];
    __shared__ unsigned int hist[64];
    __shared__ __align__(16) float ssums[4][64];

    const int blk  = blockIdx.x;        // 1024: h = low 4 bits (bi-major)
    const int h    = blk & 15;
    const int grp  = blk >> 4;          // 64 groups x 128 tokens
    const int tid  = threadIdx.x;
    const int wave = __builtin_amdgcn_readfirstlane(tid >> 6);
    const int lane = tid & 63;
    const int tk   = lane & 31;         // token within tile (C col)
    const int hi   = lane >> 5;
    const int tokb = grp * 128 + wave * 32;

    // ---- fused W conversion: frag f = ks*4+half*2+plane (R16 layout).
    // Wave w handles frag-pairs fp = w*4..w*4+3. Lane-contiguous ds_writes
    // (conflict-free). Values pre-scaled by log2(e).
    #pragma unroll
    for (int j = 0; j < 4; ++j) {
        const int fp    = wave * 4 + j;       // 0..15
        const int ks    = fp >> 1, half_ = fp & 1;
        const int s     = half_ * 32 + tk;
        const int k0    = ks * 16 + hi * 8;
        const float* src = w + (size_t)(h * NSTATE + s) * DDIM + k0;
        f32x4 v0 = *reinterpret_cast<const f32x4*>(src);
        f32x4 v1 = *reinterpret_cast<const f32x4*>(src + 4);
        #pragma unroll
        for (int i = 0; i < 4; ++i) { v0[i] *= LOG2E; v1[i] *= LOG2E; }
        half8 hv, lv;
        split8(v0, v1, hv, lv);
        *reinterpret_cast<half8*>(smem + (fp * 2)     * 1024 + lane * 16) = hv;
        *reinterpret_cast<half8*>(smem + (fp * 2 + 1) * 1024 + lane * 16) = lv;
    }
    if (tid < 64) {
        lds_bias[tid] = bias[h * NSTATE + tid] * LOG2E;
        hist[tid] = 0;
    }
    __syncthreads();   // planes + bias + hist ready

    // acc init = scaled bias (C-layout order; 8 broadcast ds_read_b128)
    f32x16 acc0, acc1;
    #pragma unroll
    for (int g = 0; g < 4; ++g) {
        f32x4 b0 = *reinterpret_cast<const f32x4*>(&lds_bias[g * 8 + hi * 4]);
        f32x4 b1 = *reinterpret_cast<const f32x4*>(&lds_bias[32 + g * 8 + hi * 4]);
        #pragma unroll
        for (int i = 0; i < 4; ++i) { acc0[g * 4 + i] = b0[i]; acc1[g * 4 + i] = b1[i]; }
    }

    const float* xrow = x + (size_t)(tokb + tk) * (NHEAD * DDIM) + h * DDIM + hi * 8;

    // ---- 8 k-steps x (2 state-halves x 3 split-terms) MFMA (R16 core) ----
    #pragma unroll
    for (int ks = 0; ks < 8; ++ks) {
        half8 wh0 = *reinterpret_cast<const half8*>(smem + (ks * 4 + 0) * 1024 + lane * 16);
        half8 wl0 = *reinterpret_cast<const half8*>(smem + (ks * 4 + 1) * 1024 + lane * 16);
        half8 wh1 = *reinterpret_cast<const half8*>(smem + (ks * 4 + 2) * 1024 + lane * 16);
        half8 wl1 = *reinterpret_cast<const half8*>(smem + (ks * 4 + 3) * 1024 + lane * 16);
        f32x4 g0 = *reinterpret_cast<const f32x4*>(xrow + ks * 16);
        f32x4 g1 = *reinterpret_cast<const f32x4*>(xrow + ks * 16 + 4);
        half8 xh, xl;
        split8(g0, g1, xh, xl);
        acc0 = __builtin_amdgcn_mfma_f32_32x32x16_f16(wh0, xh, acc0, 0, 0, 0);
        acc0 = __builtin_amdgcn_mfma_f32_32x32x16_f16(wh0, xl, acc0, 0, 0, 0);
        acc0 = __builtin_amdgcn_mfma_f32_32x32x16_f16(wl0, xh, acc0, 0, 0, 0);
        acc1 = __builtin_amdgcn_mfma_f32_32x32x16_f16(wh1, xh, acc1, 0, 0, 0);
        acc1 = __builtin_amdgcn_mfma_f32_32x32x16_f16(wh1, xl, acc1, 0, 0, 0);
        acc1 = __builtin_amdgcn_mfma_f32_32x32x16_f16(wl1, xh, acc1, 0, 0, 0);
    }

    // ---- epilogue (R16, absmax-0-verified): register-local argmax ----
    float mx = acc1[15];
    #pragma unroll
    for (int r = 14; r >= 0; --r) mx = fmaxf(mx, acc1[r]);
    #pragma unroll
    for (int r = 15; r >= 0; --r) mx = fmaxf(mx, acc0[r]);

    int idx = 0;
    #pragma unroll
    for (int r = 15; r >= 0; --r) {   // tau=1 states (32..63)
        const int s = 32 + (r & 3) + ((r >> 2) << 3) + (hi << 2);
        idx = (acc1[r] == mx) ? s : idx;
    }
    #pragma unroll
    for (int r = 15; r >= 0; --r) {   // tau=0 states (0..31)
        const int s = (r & 3) + ((r >> 2) << 3) + (hi << 2);
        idx = (acc0[r] == mx) ? s : idx;
    }
    {
        const float omx  = __shfl_xor(mx, 32);
        const int   oidx = __shfl_xor(idx, 32);
        if (omx > mx || (omx == mx && oidx < idx)) { mx = omx; idx = oidx; }
    }

    // softmax scores: logits are pre-scaled by log2e -> exp2f = native v_exp
    float sm = 0.f;
    #pragma unroll
    for (int r = 0; r < 16; ++r) { acc0[r] = exp2f(acc0[r]); sm += acc0[r]; }
    #pragma unroll
    for (int r = 0; r < 16; ++r) { acc1[r] = exp2f(acc1[r]); sm += acc1[r]; }
    sm += __shfl_xor(sm, 32);
    const float rinv = __builtin_amdgcn_rcpf(sm);

    #pragma unroll
    for (int r = 0; r < 16; ++r) {
        acc0[r] = dpp_sum32(acc0[r] * rinv);
        acc1[r] = dpp_sum32(acc1[r] * rinv);
    }
    if ((lane & 31) == 31) {          // lanes 31 (hi=0) / 63 (hi=1)
        #pragma unroll
        for (int g = 0; g < 4; ++g) {
            f32x4 p0, p1;
            #pragma unroll
            for (int i = 0; i < 4; ++i) { p0[i] = acc0[g * 4 + i]; p1[i] = acc1[g * 4 + i]; }
            *reinterpret_cast<f32x4*>(&ssums[wave][(g << 3) + (hi << 2)])      = p0;
            *reinterpret_cast<f32x4*>(&ssums[wave][32 + (g << 3) + (hi << 2)]) = p1;
        }
    }

    if (hi == 0) {
        atomicAdd(&hist[idx], 1u);
        idx_scr[(size_t)h * TOKENS + tokb + tk] = (float)idx;   // coalesced
    }

    __syncthreads();   // ssums + hist complete
    if (wave == 0) {
        const float sv = ssums[0][lane] + ssums[1][lane] + ssums[2][lane] + ssums[3][lane];
        const float cv = (float)hist[lane];
        const int rep = blk & 7;
        atomicAdd(repf + rep * 1024 + h * 64 + lane, sv);
        atomicAdd(repc + rep * 1024 + h * 64 + lane, cv);
    }
}

// finale: 257 blocks. b<256: transpose 32 tokens x 16 heads (coalesced LDS
// path) + ones plane; b==256: loss from the 8 replicas.
__global__ __launch_bounds__(256)
void finale(const float* __restrict__ idx_scr,
            const float* __restrict__ repf,
            const float* __restrict__ repc,
            float* __restrict__ out)
{
    const int b   = blockIdx.x;
    const int tid = threadIdx.x;

    if (b < 256) {
        __shared__ float tl[32][17];
        const int tk = tid & 31, hh = tid >> 5;   // hh 0..7 (+8 second pass)
        #pragma unroll
        for (int i = 0; i < 2; ++i)
            tl[tk][i * 8 + hh] = idx_scr[(size_t)(i * 8 + hh) * TOKENS + b * 32 + tk];
        __syncthreads();
        #pragma unroll
        for (int i = 0; i < 2; ++i) {
            const int o = i * 256 + tid;          // 512 outputs: [32 tok][16 heads]
            out[(size_t)TH + (size_t)b * 512 + o] = tl[o >> 4][o & 15];
            out[(size_t)b * 512 + o] = 1.0f;
        }
    } else {
        float part = 0.0f;
        for (int j = tid; j < NHEAD * NSTATE; j += 256) {
            float cf = 0.f, cc = 0.f;
            #pragma unroll
            for (int r = 0; r < 8; ++r) {
                cf += repf[r * 1024 + j];
                cc += repc[r * 1024 + j];
            }
            part += cf * cc;
        }
        #pragma unroll
        for (int d = 1; d <= 32; d <<= 1)
            part += __shfl_xor(part, d);
        __shared__ float red[4];
        const int wv = tid >> 6, lane = tid & 63;
        if (lane == 0) red[wv] = part;
        __syncthreads();
        if (tid == 0) {
            const float tot = red[0] + red[1] + red[2] + red[3];
            const float T = (float)TOKENS;
            out[2 * (size_t)TH] = tot * ((float)NSTATE / (T * T));
        }
    }
}

extern "C" void kernel_launch(void* const* d_in, const int* in_sizes, int n_in,
                              void* d_out, int out_size, void* d_ws, size_t ws_size,
                              hipStream_t stream)
{
    const float* x    = (const float*)d_in[0];
    const float* w    = (const float*)d_in[1];
    const float* bias = (const float*)d_in[2];
    float* out = (float*)d_out;

    float* repf    = (float*)d_ws;
    float* repc    = (float*)d_ws + 8192;
    float* idx_scr = (float*)((char*)d_ws + IDX_OFF);

    hipMemsetAsync(d_ws, 0, REP_BYTES, stream);
    router_all<<<dim3(1024), dim3(256), 0, stream>>>(x, w, bias,
                                                     idx_scr, repf, repc);
    finale<<<dim3(257), dim3(256), 0, stream>>>(idx_scr, repf, repc, out);
}

// Round 18
// 28.871 us; speedup vs baseline: 1.1235x; 1.1235x over previous
//
#include <hip/hip_runtime.h>

// MultiHeadRouter: B=2, L=4096, H=16, S=64, D=128
// out (float32): [T*H ones][T*H argmax-as-float][1 loss], T = 8192
//
// R18 = best-of-session recombination, no new mechanisms:
// - prep_w: R15 verbatim (64 blocks, W->f16 hi/lo fragment planes + rep zero)
// - router: R15 verbatim (16x16x32 core, 512-thr blocks, grid 1024 =
//   8 waves/SIMD occupancy cap, bi-major, coalesced idx scratch, replica
//   atomics)  [absmax 0]
// - finale: R17 verbatim (257 blocks, coalesced LDS transpose, full-line
//   writes, loss in block 256)  [absmax 0]

#define TOKENS  8192
#define NHEAD   16
#define NSTATE  64
#define DDIM    128
#define TH      (TOKENS * NHEAD)

// d_ws layout
#define WFRAG_BYTES (1u << 19)                 // 512 KB fragment planes
#define REP_OFF     WFRAG_BYTES                // 64 KB: repf[8][1024], repc[8][1024]
#define REP_BYTES   65536
#define IDX_OFF     (WFRAG_BYTES + REP_BYTES)  // 512 KB idx_scr[16][8192]

typedef _Float16 half8 __attribute__((ext_vector_type(8)));
typedef float    f32x4 __attribute__((ext_vector_type(4)));

#define GLOAD_LDS16(gsrc, ldst)                                           \
    __builtin_amdgcn_global_load_lds(                                     \
        (const __attribute__((address_space(1))) void*)(gsrc),            \
        (__attribute__((address_space(3))) void*)(ldst), 16, 0, 0)

__device__ __forceinline__ unsigned int ordf(float f) {
    unsigned int u = __float_as_uint(f);
    return (u & 0x80000000u) ? ~u : (u | 0x80000000u);   // order-preserving
}

__device__ __forceinline__ void split8(const f32x4 v0, const f32x4 v1,
                                       half8& hh, half8& ll) {
    #pragma unroll
    for (int j = 0; j < 4; ++j) {
        _Float16 h0 = (_Float16)v0[j];
        hh[j]     = h0;  ll[j]     = (_Float16)(v0[j] - (float)h0);
        _Float16 h1 = (_Float16)v1[j];
        hh[4 + j] = h1;  ll[4 + j] = (_Float16)(v1[j] - (float)h1);
    }
}

// One-shot: W fp32 -> fragment-ordered f16 hi/lo planes (R7-verified layout)
// + zero the atomic-replica region.
__global__ __launch_bounds__(256)
void prep_w(const float* __restrict__ w, half8* __restrict__ wfrag,
            float* __restrict__ rep /* 16384 floats */)
{
    const int t    = blockIdx.x * 256 + threadIdx.x;   // 16384 threads
    rep[t] = 0.0f;
    const int lane = t & 63;
    const int n    = (t >> 6) & 3;
    const int ks   = (t >> 8) & 3;
    const int h    = t >> 10;
    const int s    = n * 16 + (lane & 15);
    const int k0   = ks * 32 + (lane >> 4) * 8;
    const float* src = w + (size_t)(h * NSTATE + s) * DDIM + k0;
    f32x4 v0 = *reinterpret_cast<const f32x4*>(src);
    f32x4 v1 = *reinterpret_cast<const f32x4*>(src + 4);
    half8 hv, lv;
    split8(v0, v1, hv, lv);
    const size_t hb = (size_t)h * 2048;
    const int fb = (ks * 4 + n) * 2;
    wfrag[hb + (size_t)fb * 64 + lane]       = hv;
    wfrag[hb + (size_t)(fb + 1) * 64 + lane] = lv;
}

__global__ __launch_bounds__(512)
void router_mfma(const float* __restrict__ x,      // [T,H,D]
                 const half8* __restrict__ wfrag,  // fragment planes
                 const float* __restrict__ bias,   // [H,S]
                 float* __restrict__ idx_scr,      // [H][T] h-major idx
                 float* __restrict__ repf,         // [8][1024]
                 float* __restrict__ repc)         // [8][1024]
{
    // 32 KB: B fragment planes, shared by 8 waves.
    __shared__ __align__(16) unsigned char smem[32768];

    const int blk  = blockIdx.x;        // 1024: h = low 4 bits (bi-major)
    const int h    = blk & 15;
    const int grp  = blk >> 4;          // 64 groups x 128 tokens per head
    const int tid  = threadIdx.x;
    const int wave = __builtin_amdgcn_readfirstlane(tid >> 6);   // 0..7
    const int lane = tid & 63;
    const int col  = lane & 15;         // A-row (token low) == B-state low bits
    const int kg   = lane >> 4;
    const int tokb = grp * 128 + wave * 16;   // this wave's single tile

    // ---- stage B once per block: 32 KB linear copy, 512 threads x 4 x 16B ----
    {
        const char* wsrc = (const char*)wfrag + (size_t)h * 32768;
        #pragma unroll
        for (int i = 0; i < 4; ++i) {
            const int off = (i * 512 + tid) * 16;
            GLOAD_LDS16(wsrc + off, smem + off);
        }
    }

    const float b0 = bias[h * NSTATE +  0 + col];
    const float b1 = bias[h * NSTATE + 16 + col];
    const float b2 = bias[h * NSTATE + 32 + col];
    const float b3 = bias[h * NSTATE + 48 + col];

    __syncthreads();   // the only barrier: B planes ready

    const size_t srow = (size_t)(NHEAD * DDIM);
    const float* arow = x + (size_t)(tokb + col) * srow + h * DDIM + kg * 8;

    f32x4 acc[4];
    #pragma unroll
    for (int n = 0; n < 4; ++n) {
        f32x4 z = {0.f, 0.f, 0.f, 0.f};
        acc[n] = z;
    }

    // streamed A: 2 x f32x4 per ks (low reg demand; 8-way TLP hides latency)
    #pragma unroll
    for (int ks = 0; ks < 4; ++ks) {
        f32x4 g0 = *reinterpret_cast<const f32x4*>(arow + ks * 32);
        f32x4 g1 = *reinterpret_cast<const f32x4*>(arow + ks * 32 + 4);
        half8 ah, al;
        split8(g0, g1, ah, al);
        #pragma unroll
        for (int n = 0; n < 4; ++n) {   // chain order bit-identical R4-R15
            const int fo = (ks * 4 + n) * 2048 + lane * 16;
            half8 bh = *reinterpret_cast<const half8*>(smem + fo);
            half8 bl = *reinterpret_cast<const half8*>(smem + fo + 1024);
            acc[n] = __builtin_amdgcn_mfma_f32_16x16x32_f16(ah, bh, acc[n], 0, 0, 0);
            acc[n] = __builtin_amdgcn_mfma_f32_16x16x32_f16(ah, bl, acc[n], 0, 0, 0);
            acc[n] = __builtin_amdgcn_mfma_f32_16x16x32_f16(al, bh, acc[n], 0, 0, 0);
        }
    }

    // ---- epilogue (absmax-0-verified structure) ----
    float sc[4] = {0.f, 0.f, 0.f, 0.f};
    int   cn[4] = {0, 0, 0, 0};
    int   my_idx = 0;

    #pragma unroll
    for (int rg = 0; rg < 4; ++rg) {
        float L0 = acc[0][rg] + b0;
        float L1 = acc[1][rg] + b1;
        float L2 = acc[2][rg] + b2;
        float L3 = acc[3][rg] + b3;

        unsigned long long k0 = ((unsigned long long)ordf(L0) << 6) | (unsigned)(63 - ( 0 + col));
        unsigned long long k1 = ((unsigned long long)ordf(L1) << 6) | (unsigned)(63 - (16 + col));
        unsigned long long k2 = ((unsigned long long)ordf(L2) << 6) | (unsigned)(63 - (32 + col));
        unsigned long long k3 = ((unsigned long long)ordf(L3) << 6) | (unsigned)(63 - (48 + col));
        unsigned long long ka = k0 > k1 ? k0 : k1;
        unsigned long long kb = k2 > k3 ? k2 : k3;
        unsigned long long kk = ka > kb ? ka : kb;
        #pragma unroll
        for (int d = 1; d <= 8; d <<= 1) {
            unsigned long long o = __shfl_xor(kk, d);
            kk = kk > o ? kk : o;
        }
        const int idx = 63 - (int)(kk & 63ull);

        float e0 = __expf(L0), e1 = __expf(L1), e2 = __expf(L2), e3 = __expf(L3);
        float sm = (e0 + e1) + (e2 + e3);
        #pragma unroll
        for (int d = 1; d <= 8; d <<= 1) sm += __shfl_xor(sm, d);
        const float rinv = __builtin_amdgcn_rcpf(sm);
        sc[0] += e0 * rinv; sc[1] += e1 * rinv;
        sc[2] += e2 * rinv; sc[3] += e3 * rinv;

        cn[0] += (idx ==  0 + col);
        cn[1] += (idx == 16 + col);
        cn[2] += (idx == 32 + col);
        cn[3] += (idx == 48 + col);

        if (col == rg) my_idx = idx;    // owner lane captures its token
    }
    // 16 owner lanes (col<4) -> 64 contiguous bytes
    if (col < 4)
        idx_scr[(size_t)h * TOKENS + tokb + (kg << 2) + col] = (float)my_idx;

    // wave reduce over kg groups -> replica atomics (contention-diluted)
    #pragma unroll
    for (int n = 0; n < 4; ++n) {
        sc[n] += __shfl_xor(sc[n], 16);
        sc[n] += __shfl_xor(sc[n], 32);
        cn[n] += __shfl_xor(cn[n], 16);
        cn[n] += __shfl_xor(cn[n], 32);
    }
    if (kg == 0) {
        const int rep = ((blk << 3) | wave) & 7;
        #pragma unroll
        for (int n = 0; n < 4; ++n) {
            atomicAdd(repf + rep * 1024 + h * 64 + n * 16 + col, sc[n]);
            atomicAdd(repc + rep * 1024 + h * 64 + n * 16 + col, (float)cn[n]);
        }
    }
}

// finale (R17-verified): 257 blocks. b<256: transpose 32 tokens x 16 heads
// via padded LDS + ones plane (full-line writes); b==256: loss.
__global__ __launch_bounds__(256)
void finale(const float* __restrict__ idx_scr,
            const float* __restrict__ repf,
            const float* __restrict__ repc,
            float* __restrict__ out)
{
    const int b   = blockIdx.x;
    const int tid = threadIdx.x;

    if (b < 256) {
        __shared__ float tl[32][17];
        const int tk = tid & 31, hh = tid >> 5;   // hh 0..7 (+8 second pass)
        #pragma unroll
        for (int i = 0; i < 2; ++i)
            tl[tk][i * 8 + hh] = idx_scr[(size_t)(i * 8 + hh) * TOKENS + b * 32 + tk];
        __syncthreads();
        #pragma unroll
        for (int i = 0; i < 2; ++i) {
            const int o = i * 256 + tid;          // 512 outputs: [32 tok][16 heads]
            out[(size_t)TH + (size_t)b * 512 + o] = tl[o >> 4][o & 15];
            out[(size_t)b * 512 + o] = 1.0f;
        }
    } else {
        float part = 0.0f;
        for (int j = tid; j < NHEAD * NSTATE; j += 256) {
            float cf = 0.f, cc = 0.f;
            #pragma unroll
            for (int r = 0; r < 8; ++r) {
                cf += repf[r * 1024 + j];
                cc += repc[r * 1024 + j];
            }
            part += cf * cc;
        }
        #pragma unroll
        for (int d = 1; d <= 32; d <<= 1)
            part += __shfl_xor(part, d);
        __shared__ float red[4];
        const int wv = tid >> 6, lane = tid & 63;
        if (lane == 0) red[wv] = part;
        __syncthreads();
        if (tid == 0) {
            const float tot = red[0] + red[1] + red[2] + red[3];
            const float T = (float)TOKENS;
            out[2 * (size_t)TH] = tot * ((float)NSTATE / (T * T));
        }
    }
}

extern "C" void kernel_launch(void* const* d_in, const int* in_sizes, int n_in,
                              void* d_out, int out_size, void* d_ws, size_t ws_size,
                              hipStream_t stream)
{
    const float* x    = (const float*)d_in[0];
    const float* w    = (const float*)d_in[1];
    const float* bias = (const float*)d_in[2];
    float* out = (float*)d_out;

    half8* wfrag   = (half8*)d_ws;
    float* rep     = (float*)((char*)d_ws + REP_OFF);
    float* repf    = rep;
    float* repc    = rep + 8192;
    float* idx_scr = (float*)((char*)d_ws + IDX_OFF);

    prep_w<<<dim3(64), dim3(256), 0, stream>>>(w, wfrag, rep);
    router_mfma<<<dim3(1024), dim3(512), 0, stream>>>(x, wfrag, bias,
                                                      idx_scr, repf, repc);
    finale<<<dim3(257), dim3(256), 0, stream>>>(idx_scr, repf, repc, out);
}